// Round 9
// baseline (1459.160 us; speedup 1.0000x reference)
//
#include <hip/hip_runtime.h>
#include <hip/hip_bf16.h>

#define BQ 512
#define LQ 100
#define HQ 256
#define GQ 768
#define WINQ 5
#define MQ 95    // L - WIN
#define HPAD 264 // h_lds row pad

typedef __hip_bfloat16 bf16;
typedef unsigned short u16;
typedef __attribute__((ext_vector_type(8))) short short8;
typedef __attribute__((ext_vector_type(4))) float f32x4;
typedef __attribute__((ext_vector_type(4))) int int4v;

__device__ __forceinline__ float bf2f(bf16 v) { return __bfloat162float(v); }
__device__ __forceinline__ bf16 f2bf(float v) { return __float2bfloat16(v); }
__device__ __forceinline__ u16 f2bfb(float v) { return __builtin_bit_cast(u16, __float2bfloat16(v)); }
__device__ __forceinline__ float bfb2f(u16 u) {
  unsigned int x = ((unsigned int)u) << 16;
  return __builtin_bit_cast(float, x);
}
__device__ __forceinline__ float rcpf(float x) { return __builtin_amdgcn_rcpf(x); }
__device__ __forceinline__ float sigmf(float x) { return rcpf(1.0f + __expf(-x)); }
__device__ __forceinline__ float tanh_fast(float x) {
  float ax = fabsf(x);
  float e = __expf(-2.0f * ax);
  float t = (1.0f - e) * rcpf(1.0f + e);
  return copysignf(t, x);
}
__device__ __forceinline__ short8 ld8(const u16* p) { return *(const short8*)p; }
__device__ __forceinline__ void st8nt(u16* p, short8 v) {
  __builtin_nontemporal_store(v, (short8*)p);
}
__device__ __forceinline__ f32x4 mfma16(short8 a, short8 b, f32x4 c) {
  return __builtin_amdgcn_mfma_f32_16x16x32_bf16(a, b, c, 0, 0, 0);
}
// pin into the VGPR bank (v0-v255)
__device__ __forceinline__ void pin8(short8& v) {
  int4v t = __builtin_bit_cast(int4v, v);
  asm volatile("" : "+v"(t));
  v = __builtin_bit_cast(short8, t);
}
// pin into the AGPR bank (a0-a255) — the other half of gfx950's unified
// 512-reg file. MFMA reads B operands from AGPRs natively, so these stay
// resident without consuming the 256-entry VGPR encoding space.
__device__ __forceinline__ void pin8a(short8& v) {
  int4v t = __builtin_bit_cast(int4v, v);
  asm volatile("" : "+a"(t));
  v = __builtin_bit_cast(short8, t);
}
// async global->LDS, 16B per lane; LDS dest = wave-uniform base + lane*16
__device__ __forceinline__ void gl_lds16(const u16* g, u16* l) {
  __builtin_amdgcn_global_load_lds(
      (const __attribute__((address_space(1))) unsigned int*)g,
      (__attribute__((address_space(3))) unsigned int*)l, 16, 0, 0);
}
// xwl swizzled layout: chunk (ch = col>>3) for batch-row m lives at slot
// ch*16 + (m ^ (ch&15)); u16 index = slot*8 + (col&7)
__device__ __forceinline__ int xwl_idx(int col, int m) {
  int ch = col >> 3;
  return ch * 128 + ((m ^ (ch & 15)) << 3) + (col & 7);
}

// ---------------- all fp32 -> bf16 weight conversions in one launch --------
__global__ __launch_bounds__(256) void cvt7_kernel(
    const float* __restrict__ s0, const float* __restrict__ s1,
    const float* __restrict__ s2, const float* __restrict__ s3,
    const float* __restrict__ s4, const float* __restrict__ s5,
    const float* __restrict__ s6,
    u16* __restrict__ d0, u16* __restrict__ d1, u16* __restrict__ d2,
    u16* __restrict__ d3, u16* __restrict__ d4, u16* __restrict__ d5,
    u16* __restrict__ d6) {
  const int seg = blockIdx.y;
  const float* s; u16* d; int n4;
  switch (seg) {
    case 0: s = s0; d = d0; n4 = GQ * HQ / 4; break;
    case 1: s = s1; d = d1; n4 = GQ * HQ / 4; break;
    case 2: s = s2; d = d2; n4 = GQ * HQ / 4; break;
    case 3: s = s3; d = d3; n4 = GQ * HQ / 4; break;
    case 4: s = s4; d = d4; n4 = GQ * HQ / 4; break;
    case 5: s = s5; d = d5; n4 = GQ * HQ / 4; break;
    default: s = s6; d = d6; n4 = HQ * 512 / 4; break;
  }
  int i = blockIdx.x * 256 + threadIdx.x;
  if (i < n4) {
    float4 v = reinterpret_cast<const float4*>(s)[i];
    ushort4 o;
    o.x = f2bfb(v.x); o.y = f2bfb(v.y); o.z = f2bfb(v.z); o.w = f2bfb(v.w);
    reinterpret_cast<ushort4*>(d)[i] = o;
  }
}

// ---------------- xw0: x(B,L,3) @ Wih0^T + bih0 -> bf16 [row][768] ---------
__global__ __launch_bounds__(256) void xw0_kernel(
    const float* __restrict__ x,
    const float* __restrict__ WihA, const float* __restrict__ bihA,
    const float* __restrict__ WihB, const float* __restrict__ bihB,
    u16* __restrict__ xw) {
  const int r = blockIdx.y;
  const float* Wih = r ? WihB : WihA;
  const float* bih = r ? bihB : bihA;
  const int row0 = blockIdx.x * 16;
  u16* o = xw + (size_t)r * BQ * LQ * GQ;
  const int g = threadIdx.x;

  __shared__ float xs[16][3];
  if (threadIdx.x < 48) {
    int m = threadIdx.x / 3, i = threadIdx.x - m * 3;
    xs[m][i] = x[(size_t)(row0 + m) * 3 + i];
  }
  float wv[3][3], bv[3];
  #pragma unroll
  for (int s = 0; s < 3; ++s) {
    int gg = g + s * 256;
    wv[s][0] = Wih[gg * 3]; wv[s][1] = Wih[gg * 3 + 1]; wv[s][2] = Wih[gg * 3 + 2];
    bv[s] = bih[gg];
  }
  __syncthreads();
  for (int m = 0; m < 16; ++m) {
    const float x0 = xs[m][0], x1 = xs[m][1], x2 = xs[m][2];
    u16* orow = o + (size_t)(row0 + m) * GQ;
    #pragma unroll
    for (int s = 0; s < 3; ++s)
      orow[s * 256 + g] = f2bfb(fmaf(x0, wv[s][0], fmaf(x1, wv[s][1], fmaf(x2, wv[s][2], bv[s]))));
  }
}

// ---------------- xw1: o0(51200,256)bf16 @ Wih1^T + bih1 -> bf16 -----------
__global__ __launch_bounds__(256) void xw1_gemm_kernel(
    const u16* __restrict__ o0A, const u16* __restrict__ o0B,
    const u16* __restrict__ wihA, const u16* __restrict__ wihB,
    const float* __restrict__ bihA, const float* __restrict__ bihB,
    u16* __restrict__ xw) {
  const int r = blockIdx.y;
  const u16* A = r ? o0B : o0A;
  const u16* Wih = r ? wihB : wihA;
  const float* bih = r ? bihB : bihA;
  u16* out = xw + (size_t)r * BQ * LQ * GQ;
  const int row0 = blockIdx.x * 64;
  const int tid = threadIdx.x;
  const int w = tid >> 6, lane = tid & 63, l15 = lane & 15, quad = lane >> 4;

  __shared__ u16 a_lds[64][HPAD];
  for (int g = tid; g < 64 * 32; g += 256) {           // 16B groups
    int rr = g >> 5, c8 = (g & 31) * 8;
    *(short8*)&a_lds[rr][c8] = ld8(&A[(size_t)(row0 + rr) * HQ + c8]);
  }
  __syncthreads();

  for (int nt = 0; nt < 12; ++nt) {
    const int n0 = w * 192 + nt * 16;
    const u16* bp = Wih + (size_t)(n0 + l15) * HQ + quad * 8;
    short8 b[8];
    #pragma unroll
    for (int kt = 0; kt < 8; ++kt) b[kt] = ld8(bp + kt * 32);
    const float bias = bih[n0 + l15];
    #pragma unroll
    for (int mt = 0; mt < 4; ++mt) {
      f32x4 acc = {bias, bias, bias, bias};
      #pragma unroll
      for (int kt = 0; kt < 8; ++kt) {
        short8 a = ld8(&a_lds[mt * 16 + l15][kt * 32 + quad * 8]);
        acc = mfma16(a, b[kt], acc);
      }
      #pragma unroll
      for (int reg = 0; reg < 4; ++reg) {
        int row = row0 + mt * 16 + quad * 4 + reg;
        out[(size_t)row * GQ + n0 + l15] = f2bfb(acc[reg]);
      }
    }
  }
}

// ---------------- MFMA GRU scan: AGPR+VGPR resident Whh, 1 wave/SIMD -------
// 256 thr (4 waves), 16 batch rows/block. Wave w owns hidden cols
// [w*64, w*64+64): bb[12][8] = 384 fragment regs, split 8 tiles -> AGPR
// ("+a", 256 regs) + 4 tiles -> VGPR ("+v", 128 regs). R7 proved
// waves_per_eu(1,1) yields a full 256-entry VGPR budget with no scratch;
// its failure was 384 "+v" pins > 256 VGPR encoding space. MFMA reads B
// from AGPRs natively, so the a-bank pins cost nothing per use.
__global__ __attribute__((amdgpu_flat_work_group_size(256, 256),
                          amdgpu_waves_per_eu(1, 1)))
void scan_mfma_kernel(
    const u16* __restrict__ xwA, const u16* __restrict__ xwB,
    const u16* __restrict__ whhA, const u16* __restrict__ whhB,
    const float* __restrict__ bhhA, const float* __restrict__ bhhB,
    u16* __restrict__ outA, u16* __restrict__ outB) {
  const int r = blockIdx.y;
  const u16* xw = r ? xwB : xwA;
  const u16* whh = r ? whhB : whhA;
  const float* bhh = r ? bhhB : bhhA;
  u16* out = r ? outB : outA;
  const int b0 = blockIdx.x * 16;
  const int tid = threadIdx.x;
  const int w = tid >> 6, lane = tid & 63, l15 = lane & 15, quad = lane >> 4;
  const int jbase = w * 64;

  __shared__ u16 h_lds[2][16][HPAD];
  __shared__ u16 xwl[2][16 * GQ];   // swizzled chunk layout (see xwl_idx)

  for (int i = tid; i < 16 * HPAD; i += 256)
    h_lds[0][i / HPAD][i % HPAD] = 0;

  // resident Whh slice: tile i = g*4+jt, n = g*256 + jbase + jt*16 + l15
  short8 bb[12][8];
  #pragma unroll
  for (int i = 0; i < 12; ++i) {
    const u16* bp = whh + (size_t)((i >> 2) * HQ + jbase + (i & 3) * 16 + l15) * HQ + quad * 8;
    #pragma unroll
    for (int kt = 0; kt < 8; ++kt) {
      bb[i][kt] = ld8(bp + kt * 32);
      if (i < 8) pin8a(bb[i][kt]); else pin8(bb[i][kt]);
    }
  }
  float bh[12];
  #pragma unroll
  for (int i = 0; i < 12; ++i)
    bh[i] = bhh[(i >> 2) * HQ + jbase + (i & 3) * 16 + l15];

  // xw staging: 1536 16B-chunks/step; wave w issues 6 calls of 64 chunks.
  // slot s -> (ch = s>>4, m = (s&15) ^ (ch&15))
  const u16* gsrc[6];
  int ldsoff[6];
  #pragma unroll
  for (int k = 0; k < 6; ++k) {
    int c0k = w * 384 + k * 64;
    int s = c0k + lane;
    int ch = s >> 4;
    int m = (s & 15) ^ (ch & 15);
    gsrc[k] = xw + (size_t)(b0 + m) * LQ * GQ + ch * 8;
    ldsoff[k] = c0k * 8;   // u16 units; +lane*16B by HW
  }
  // out readback: 2 chunks/thread (16 rows x 32 chunks)
  const int om0 = tid >> 5, oc0 = (tid & 31) * 8;
  const int om1 = om0 + 8;

  // stage xw(0) into xwl[0]
  #pragma unroll
  for (int k = 0; k < 6; ++k) gl_lds16(gsrc[k], &xwl[0][ldsoff[k]]);

  __syncthreads();

  for (int t = 0; t < LQ; ++t) {
    const int rb = t & 1, wb = rb ^ 1;

    // async prefetch xw(t+1) -> xwl[wb]; drained by barrier at loop end
    const int tn = (t + 1 < LQ) ? t + 1 : t;
    #pragma unroll
    for (int k = 0; k < 6; ++k)
      gl_lds16(gsrc[k] + (size_t)tn * GQ, &xwl[wb][ldsoff[k]]);

    // A fragments from LDS h(t)
    short8 a[8];
    #pragma unroll
    for (int kt = 0; kt < 8; ++kt)
      a[kt] = ld8(&h_lds[rb][l15][kt * 32 + quad * 8]);

    // out(t-1) = h_lds[rb]: coalesced readback + nontemporal store
    if (t > 0) {
      short8 h0 = ld8(&h_lds[rb][om0][oc0]);
      short8 h1 = ld8(&h_lds[rb][om1][oc0]);
      st8nt(&out[((size_t)(b0 + om0) * LQ + (t - 1)) * HQ + oc0], h0);
      st8nt(&out[((size_t)(b0 + om1) * LQ + (t - 1)) * HQ + oc0], h1);
    }

    // 4 j-slices; 3 gate accs live at a time
    #pragma unroll
    for (int jt = 0; jt < 4; ++jt) {
      f32x4 accr = {bh[jt], bh[jt], bh[jt], bh[jt]};
      f32x4 accz = {bh[4 + jt], bh[4 + jt], bh[4 + jt], bh[4 + jt]};
      f32x4 accn = {bh[8 + jt], bh[8 + jt], bh[8 + jt], bh[8 + jt]};
      #pragma unroll
      for (int kt = 0; kt < 8; ++kt) {
        accr = mfma16(a[kt], bb[jt][kt], accr);
        accz = mfma16(a[kt], bb[4 + jt][kt], accz);
        accn = mfma16(a[kt], bb[8 + jt][kt], accn);
      }
      const int j = jbase + jt * 16 + l15;
      #pragma unroll
      for (int reg = 0; reg < 4; ++reg) {
        const int m = quad * 4 + reg;
        const float xr = bfb2f(xwl[rb][xwl_idx(j, m)]);
        const float xz = bfb2f(xwl[rb][xwl_idx(HQ + j, m)]);
        const float xn = bfb2f(xwl[rb][xwl_idx(2 * HQ + j, m)]);
        const float hold = bfb2f(h_lds[rb][m][j]);
        const float rg = sigmf(accr[reg] + xr);
        const float zg = sigmf(accz[reg] + xz);
        const float ng = tanh_fast(fmaf(rg, accn[reg], xn));
        const float hn = fmaf(zg, hold - ng, ng);
        h_lds[wb][m][j] = f2bfb(hn);
      }
    }
    __syncthreads();
  }

  // final out(99): h(100) lives in h_lds[LQ & 1] == h_lds[0]
  {
    short8 h0 = ld8(&h_lds[0][om0][oc0]);
    short8 h1 = ld8(&h_lds[0][om1][oc0]);
    st8nt(&out[((size_t)(b0 + om0) * LQ + (LQ - 1)) * HQ + oc0], h0);
    st8nt(&out[((size_t)(b0 + om1) * LQ + (LQ - 1)) * HQ + oc0], h1);
  }
}

// ------- fused attention: q/e dots + softmax + windowed context ------------
__global__ __launch_bounds__(256) void attn_fused_kernel(
    const u16* __restrict__ out1, const u16* __restrict__ out2,
    const float* __restrict__ attn_w,
    u16* __restrict__ c1, u16* __restrict__ c2) {
  const int b = blockIdx.x;
  const int br = blockIdx.y;
  const u16* out = br ? out2 : out1;
  u16* cb = br ? c2 : c1;
  const int tid = threadIdx.x;
  const int w = tid >> 6, lane = tid & 63;

  __shared__ u16 ol[LQ][HPAD];
  __shared__ float qv[LQ], ev[LQ];

  for (int idx = tid; idx < LQ * 32; idx += 256) {
    int row = idx >> 5, c8 = (idx & 31) * 8;
    *(short8*)&ol[row][c8] = ld8(&out[((size_t)b * LQ + row) * HQ + c8]);
  }
  __syncthreads();

  float aq[4], ae[4];
  #pragma unroll
  for (int jj = 0; jj < 4; ++jj) {
    aq[jj] = attn_w[lane + 64 * jj];
    ae[jj] = attn_w[HQ + lane + 64 * jj];
  }
  for (int l = w; l < LQ; l += 4) {
    float sq = 0.f, se = 0.f;
    #pragma unroll
    for (int jj = 0; jj < 4; ++jj) {
      float v = bfb2f(ol[l][lane + 64 * jj]);
      sq = fmaf(v, aq[jj], sq);
      se = fmaf(v, ae[jj], se);
    }
    #pragma unroll
    for (int o = 32; o > 0; o >>= 1) { sq += __shfl_down(sq, o); se += __shfl_down(se, o); }
    if (lane == 0) { qv[l] = sq; ev[l] = se; }
  }
  __syncthreads();

  for (int m = 0; m < MQ; ++m) {
    const float qq = qv[m + WINQ];
    float s[WINQ];
    float mx = -1e30f;
    #pragma unroll
    for (int k = 0; k < WINQ; ++k) { s[k] = qq + ev[m + k]; mx = fmaxf(mx, s[k]); }
    float sum = 0.f;
    #pragma unroll
    for (int k = 0; k < WINQ; ++k) { s[k] = __expf(s[k] - mx); sum += s[k]; }
    const float inv = rcpf(sum);
    float accv = 0.f;
    #pragma unroll
    for (int k = 0; k < WINQ; ++k)
      accv = fmaf(s[k], bfb2f(ol[m + k][tid]), accv);
    cb[((size_t)b * MQ + m) * HQ + tid] = f2bfb(accv * inv);
  }
}

// ---------------- fused FC via MFMA: [c | out] @ fcW^T + fcb ---------------
__global__ __launch_bounds__(256) void fc_mfma_kernel(
    const u16* __restrict__ c1, const u16* __restrict__ c2,
    const u16* __restrict__ o1, const u16* __restrict__ o2,
    const u16* __restrict__ fcw, const float* __restrict__ fcb,
    u16* __restrict__ f1, u16* __restrict__ f2) {
  const int br = blockIdx.y;
  const u16* cb = br ? c2 : c1;
  const u16* ob = br ? o2 : o1;
  u16* fo = br ? f2 : f1;
  const int i0 = blockIdx.x * 64;
  const int tid = threadIdx.x;
  const int w = tid >> 6, lane = tid & 63, l15 = lane & 15, quad = lane >> 4;

  __shared__ u16 a_lds[64][520];
  for (int g = tid; g < 64 * 64; g += 256) {        // 16B groups, K=512
    int rr = g >> 6, c8 = (g & 63) * 8;
    int gi = i0 + rr;
    int bb = gi / MQ, mm = gi - bb * MQ;
    const u16* src = (c8 < HQ) ? &cb[(size_t)gi * HQ + c8]
                               : &ob[((size_t)bb * LQ + mm + WINQ) * HQ + (c8 - HQ)];
    *(short8*)&a_lds[rr][c8] = ld8(src);
  }
  __syncthreads();

  for (int nt = 0; nt < 4; ++nt) {
    const int n0 = w * 64 + nt * 16;
    const u16* bp = fcw + (size_t)(n0 + l15) * 512 + quad * 8;
    short8 b[16];
    #pragma unroll
    for (int kt = 0; kt < 16; ++kt) b[kt] = ld8(bp + kt * 32);
    const float bias = fcb[n0 + l15];
    #pragma unroll
    for (int mt = 0; mt < 4; ++mt) {
      f32x4 acc = {bias, bias, bias, bias};
      #pragma unroll
      for (int kt = 0; kt < 16; ++kt) {
        short8 a = ld8(&a_lds[mt * 16 + l15][kt * 32 + quad * 8]);
        acc = mfma16(a, b[kt], acc);
      }
      #pragma unroll
      for (int reg = 0; reg < 4; ++reg)
        fo[(size_t)(i0 + mt * 16 + quad * 4 + reg) * HQ + n0 + l15] = f2bfb(acc[reg]);
    }
  }
}

// ---------------- final head -----------------------------------------------
__global__ __launch_bounds__(256) void final_kernel(
    const bf16* __restrict__ out1,
    const bf16* __restrict__ f1, const bf16* __restrict__ f2,
    const float* __restrict__ outW, const float* __restrict__ outb,
    float* __restrict__ dout) {
  const int wid = blockIdx.x * 4 + (threadIdx.x >> 6);
  const int lane = threadIdx.x & 63;
  const int b = wid / LQ, l = wid - b * LQ;
  const bf16* s1 = (l < WINQ) ? (out1 + ((size_t)b * LQ + l) * HQ)
                              : (f1 + ((size_t)b * MQ + (l - WINQ)) * HQ);
  int l2 = l + 10;  // D = 10
  if (l2 > LQ - 1) l2 = LQ - 1;
  const bf16* s2 = f2 + ((size_t)b * MQ + (l2 - WINQ)) * HQ;
  float s = 0.0f;
  #pragma unroll
  for (int jj = 0; jj < 4; ++jj) {
    int h = lane + jj * 64;
    s = fmaf(bf2f(s1[h]), outW[h], s);
    s = fmaf(bf2f(s2[h]), outW[HQ + h], s);
  }
  #pragma unroll
  for (int o = 32; o > 0; o >>= 1) s += __shfl_down(s, o);
  if (lane == 0) dout[wid] = sigmf(s + outb[0]);
}

extern "C" void kernel_launch(void* const* d_in, const int* in_sizes, int n_in,
                              void* d_out, int out_size, void* d_ws, size_t ws_size,
                              hipStream_t stream) {
  const float* x       = (const float*)d_in[0];
  const float* r1_Wih0 = (const float*)d_in[1];
  const float* r1_Whh0 = (const float*)d_in[2];
  const float* r1_bih0 = (const float*)d_in[3];
  const float* r1_bhh0 = (const float*)d_in[4];
  const float* r1_Wih1 = (const float*)d_in[5];
  const float* r1_Whh1 = (const float*)d_in[6];
  const float* r1_bih1 = (const float*)d_in[7];
  const float* r1_bhh1 = (const float*)d_in[8];
  const float* r2_Wih0 = (const float*)d_in[9];
  const float* r2_Whh0 = (const float*)d_in[10];
  const float* r2_bih0 = (const float*)d_in[11];
  const float* r2_bhh0 = (const float*)d_in[12];
  const float* r2_Wih1 = (const float*)d_in[13];
  const float* r2_Whh1 = (const float*)d_in[14];
  const float* r2_bih1 = (const float*)d_in[15];
  const float* r2_bhh1 = (const float*)d_in[16];
  const float* attn_w  = (const float*)d_in[17];
  const float* fc_W    = (const float*)d_in[18];
  const float* fc_b    = (const float*)d_in[19];
  const float* out_W   = (const float*)d_in[20];
  const float* out_b   = (const float*)d_in[21];

  char* p = (char*)d_ws;
  auto carve = [&](size_t bytes) {
    char* r = p;
    p += ((bytes + 255) / 256) * 256;
    return r;
  };
  const size_t WSZ = (size_t)GQ * HQ;            // 196608 (Whh/Wih1)
  const size_t XWR = (size_t)BQ * LQ * GQ;       // 39,321,600 per receiver
  const size_t SEQ = (size_t)BQ * LQ * HQ;       // 13,107,200
  const size_t FSEQ = (size_t)BQ * MQ * HQ;      // 12,451,840

  u16* whh0A = (u16*)carve(WSZ * 2);
  u16* whh0B = (u16*)carve(WSZ * 2);
  u16* whh1A = (u16*)carve(WSZ * 2);
  u16* whh1B = (u16*)carve(WSZ * 2);
  u16* wih1A = (u16*)carve(WSZ * 2);
  u16* wih1B = (u16*)carve(WSZ * 2);
  u16* fcwbf = (u16*)carve((size_t)HQ * 512 * 2);
  u16* xwbuf = (u16*)carve(XWR * 2 * 2);         // both receivers; reused L0 then L1
  u16* obuf  = (u16*)carve(SEQ * 2 * 2);         // L0 out; later overwritten by L1 out

  u16* xwA = xwbuf;
  u16* xwB = xwbuf + XWR;
  u16* oA  = obuf;
  u16* oB  = obuf + SEQ;
  // c/f alias the xw region (dead after layer-1 scan)
  u16* c1 = xwbuf;
  u16* c2 = c1 + FSEQ;
  u16* f1 = c2 + FSEQ;
  u16* f2 = f1 + FSEQ;

  // all weight conversions, one launch
  cvt7_kernel<<<dim3((WSZ / 4 + 255) / 256, 7), 256, 0, stream>>>(
      r1_Whh0, r2_Whh0, r1_Whh1, r2_Whh1, r1_Wih1, r2_Wih1, fc_W,
      whh0A, whh0B, whh1A, whh1B, wih1A, wih1B, fcwbf);

  // layer 0
  xw0_kernel<<<dim3(BQ * LQ / 16, 2), 256, 0, stream>>>(
      x, r1_Wih0, r1_bih0, r2_Wih0, r2_bih0, xwbuf);
  scan_mfma_kernel<<<dim3(BQ / 16, 2), 256, 0, stream>>>(
      xwA, xwB, whh0A, whh0B, r1_bhh0, r2_bhh0, oA, oB);
  // layer 1
  xw1_gemm_kernel<<<dim3(BQ * LQ / 64, 2), 256, 0, stream>>>(
      oA, oB, wih1A, wih1B, r1_bih1, r2_bih1, xwbuf);
  scan_mfma_kernel<<<dim3(BQ / 16, 2), 256, 0, stream>>>(
      xwA, xwB, whh1A, whh1B, r1_bhh1, r2_bhh1, oA, oB);

  // branch
  attn_fused_kernel<<<dim3(BQ, 2), 256, 0, stream>>>(oA, oB, attn_w, c1, c2);
  fc_mfma_kernel<<<dim3((BQ * MQ) / 64, 2), 256, 0, stream>>>(c1, c2, oA, oB, fcwbf, fc_b, f1, f2);
  final_kernel<<<(BQ * LQ) / 4, 256, 0, stream>>>(
      (const bf16*)oA, (const bf16*)f1, (const bf16*)f2, out_W, out_b, (float*)d_out);
}

// Round 10
// 995.987 us; speedup vs baseline: 1.4650x; 1.4650x over previous
//
#include <hip/hip_runtime.h>
#include <hip/hip_bf16.h>

#define BQ 512
#define LQ 100
#define HQ 256
#define GQ 768
#define WINQ 5
#define MQ 95    // L - WIN
#define HPAD 264 // h_lds row pad

typedef __hip_bfloat16 bf16;
typedef unsigned short u16;
typedef __attribute__((ext_vector_type(8))) short short8;
typedef __attribute__((ext_vector_type(4))) float f32x4;

__device__ __forceinline__ float bf2f(bf16 v) { return __bfloat162float(v); }
__device__ __forceinline__ bf16 f2bf(float v) { return __float2bfloat16(v); }
__device__ __forceinline__ u16 f2bfb(float v) { return __builtin_bit_cast(u16, __float2bfloat16(v)); }
__device__ __forceinline__ float bfb2f(u16 u) {
  unsigned int x = ((unsigned int)u) << 16;
  return __builtin_bit_cast(float, x);
}
__device__ __forceinline__ float rcpf(float x) { return __builtin_amdgcn_rcpf(x); }
__device__ __forceinline__ float sigmf(float x) { return rcpf(1.0f + __expf(-x)); }
__device__ __forceinline__ float tanh_fast(float x) {
  float ax = fabsf(x);
  float e = __expf(-2.0f * ax);
  float t = (1.0f - e) * rcpf(1.0f + e);
  return copysignf(t, x);
}
__device__ __forceinline__ short8 ld8(const u16* p) { return *(const short8*)p; }
__device__ __forceinline__ void st8nt(u16* p, short8 v) {
  __builtin_nontemporal_store(v, (short8*)p);
}
__device__ __forceinline__ f32x4 mfma16(short8 a, short8 b, f32x4 c) {
  return __builtin_amdgcn_mfma_f32_16x16x32_bf16(a, b, c, 0, 0, 0);
}
// async global->LDS, 16B per lane; LDS dest = wave-uniform base + lane*16
__device__ __forceinline__ void gl_lds16(const u16* g, u16* l) {
  __builtin_amdgcn_global_load_lds(
      (const __attribute__((address_space(1))) unsigned int*)g,
      (__attribute__((address_space(3))) unsigned int*)l, 16, 0, 0);
}
// xwl swizzled layout: chunk (ch = col>>3) for batch-row m lives at slot
// ch*16 + (m ^ (ch&15)); u16 index = slot*8 + (col&7)
__device__ __forceinline__ int xwl_idx(int col, int m) {
  int ch = col >> 3;
  return ch * 128 + ((m ^ (ch & 15)) << 3) + (col & 7);
}

// ---------------- all fp32 -> bf16 weight conversions in one launch --------
__global__ __launch_bounds__(256) void cvt7_kernel(
    const float* __restrict__ s0, const float* __restrict__ s1,
    const float* __restrict__ s2, const float* __restrict__ s3,
    const float* __restrict__ s4, const float* __restrict__ s5,
    const float* __restrict__ s6,
    u16* __restrict__ d0, u16* __restrict__ d1, u16* __restrict__ d2,
    u16* __restrict__ d3, u16* __restrict__ d4, u16* __restrict__ d5,
    u16* __restrict__ d6) {
  const int seg = blockIdx.y;
  const float* s; u16* d; int n4;
  switch (seg) {
    case 0: s = s0; d = d0; n4 = GQ * HQ / 4; break;
    case 1: s = s1; d = d1; n4 = GQ * HQ / 4; break;
    case 2: s = s2; d = d2; n4 = GQ * HQ / 4; break;
    case 3: s = s3; d = d3; n4 = GQ * HQ / 4; break;
    case 4: s = s4; d = d4; n4 = GQ * HQ / 4; break;
    case 5: s = s5; d = d5; n4 = GQ * HQ / 4; break;
    default: s = s6; d = d6; n4 = HQ * 512 / 4; break;
  }
  int i = blockIdx.x * 256 + threadIdx.x;
  if (i < n4) {
    float4 v = reinterpret_cast<const float4*>(s)[i];
    ushort4 o;
    o.x = f2bfb(v.x); o.y = f2bfb(v.y); o.z = f2bfb(v.z); o.w = f2bfb(v.w);
    reinterpret_cast<ushort4*>(d)[i] = o;
  }
}

// ---------------- xw0: x(B,L,3) @ Wih0^T + bih0 -> bf16 [row][768] ---------
__global__ __launch_bounds__(256) void xw0_kernel(
    const float* __restrict__ x,
    const float* __restrict__ WihA, const float* __restrict__ bihA,
    const float* __restrict__ WihB, const float* __restrict__ bihB,
    u16* __restrict__ xw) {
  const int r = blockIdx.y;
  const float* Wih = r ? WihB : WihA;
  const float* bih = r ? bihB : bihA;
  const int row0 = blockIdx.x * 16;
  u16* o = xw + (size_t)r * BQ * LQ * GQ;
  const int g = threadIdx.x;

  __shared__ float xs[16][3];
  if (threadIdx.x < 48) {
    int m = threadIdx.x / 3, i = threadIdx.x - m * 3;
    xs[m][i] = x[(size_t)(row0 + m) * 3 + i];
  }
  float wv[3][3], bv[3];
  #pragma unroll
  for (int s = 0; s < 3; ++s) {
    int gg = g + s * 256;
    wv[s][0] = Wih[gg * 3]; wv[s][1] = Wih[gg * 3 + 1]; wv[s][2] = Wih[gg * 3 + 2];
    bv[s] = bih[gg];
  }
  __syncthreads();
  for (int m = 0; m < 16; ++m) {
    const float x0 = xs[m][0], x1 = xs[m][1], x2 = xs[m][2];
    u16* orow = o + (size_t)(row0 + m) * GQ;
    #pragma unroll
    for (int s = 0; s < 3; ++s)
      orow[s * 256 + g] = f2bfb(fmaf(x0, wv[s][0], fmaf(x1, wv[s][1], fmaf(x2, wv[s][2], bv[s]))));
  }
}

// ---------------- xw1: o0(51200,256)bf16 @ Wih1^T + bih1 -> bf16 -----------
__global__ __launch_bounds__(256) void xw1_gemm_kernel(
    const u16* __restrict__ o0A, const u16* __restrict__ o0B,
    const u16* __restrict__ wihA, const u16* __restrict__ wihB,
    const float* __restrict__ bihA, const float* __restrict__ bihB,
    u16* __restrict__ xw) {
  const int r = blockIdx.y;
  const u16* A = r ? o0B : o0A;
  const u16* Wih = r ? wihB : wihA;
  const float* bih = r ? bihB : bihA;
  u16* out = xw + (size_t)r * BQ * LQ * GQ;
  const int row0 = blockIdx.x * 64;
  const int tid = threadIdx.x;
  const int w = tid >> 6, lane = tid & 63, l15 = lane & 15, quad = lane >> 4;

  __shared__ u16 a_lds[64][HPAD];
  for (int g = tid; g < 64 * 32; g += 256) {           // 16B groups
    int rr = g >> 5, c8 = (g & 31) * 8;
    *(short8*)&a_lds[rr][c8] = ld8(&A[(size_t)(row0 + rr) * HQ + c8]);
  }
  __syncthreads();

  for (int nt = 0; nt < 12; ++nt) {
    const int n0 = w * 192 + nt * 16;
    const u16* bp = Wih + (size_t)(n0 + l15) * HQ + quad * 8;
    short8 b[8];
    #pragma unroll
    for (int kt = 0; kt < 8; ++kt) b[kt] = ld8(bp + kt * 32);
    const float bias = bih[n0 + l15];
    #pragma unroll
    for (int mt = 0; mt < 4; ++mt) {
      f32x4 acc = {bias, bias, bias, bias};
      #pragma unroll
      for (int kt = 0; kt < 8; ++kt) {
        short8 a = ld8(&a_lds[mt * 16 + l15][kt * 32 + quad * 8]);
        acc = mfma16(a, b[kt], acc);
      }
      #pragma unroll
      for (int reg = 0; reg < 4; ++reg) {
        int row = row0 + mt * 16 + quad * 4 + reg;
        out[(size_t)row * GQ + n0 + l15] = f2bfb(acc[reg]);
      }
    }
  }
}

// ---------------- MFMA GRU scan: R5 streaming + partial LDS Whh cache ------
// 512 thr (8 waves), 16 batch rows/block, wave w owns cols [w*32,w*32+32).
// NO register pinning (R6-R9 all lost to the allocator: spill/churn/agpr
// moves). Whh streamed from L2 per step (compiler-scheduled remat, 128 VGPR,
// 2 waves/SIMD) with 80 KB of it cached in LDS (10 of 48 frags/wave,
// wave-private, written once) -> per-step L2 stream 384->304 KB/CU.
// xw staged via async global_load_lds, XOR-swizzled chunk layout.
__global__ __launch_bounds__(512, 2) void scan_mfma_kernel(
    const u16* __restrict__ xwA, const u16* __restrict__ xwB,
    const u16* __restrict__ whhA, const u16* __restrict__ whhB,
    const float* __restrict__ bhhA, const float* __restrict__ bhhB,
    u16* __restrict__ outA, u16* __restrict__ outB) {
  const int r = blockIdx.y;
  const u16* xw = r ? xwB : xwA;
  const u16* whh = r ? whhB : whhA;
  const float* bhh = r ? bhhB : bhhA;
  u16* out = r ? outB : outA;
  const int b0 = blockIdx.x * 16;
  const int tid = threadIdx.x;
  const int w = tid >> 6, lane = tid & 63, l15 = lane & 15, quad = lane >> 4;
  const int jbase = w * 32;

  __shared__ u16 h_lds[2][16][HPAD];
  __shared__ u16 xwl[2][16 * GQ];     // swizzled chunk layout (see xwl_idx)
  __shared__ u16 wc[8][10][512];      // 80 KB Whh cache: frag f=i*2+kt (i<5,kt<2)

  for (int i = tid; i < 16 * HPAD; i += 512)
    h_lds[0][i / HPAD][i % HPAD] = 0;

  // tile i = g*2+jt -> gate row n = (i>>1)*256 + jbase + (i&1)*16 + l15
  // cache frags (i<5, kt<2) into wave-private LDS (no barrier needed: each
  // wave reads only its own region)
  #pragma unroll
  for (int i = 0; i < 5; ++i) {
    const u16* bp = whh + (size_t)((i >> 1) * HQ + jbase + (i & 1) * 16 + l15) * HQ + quad * 8;
    #pragma unroll
    for (int kt = 0; kt < 2; ++kt)
      *(short8*)&wc[w][i * 2 + kt][lane * 8] = ld8(bp + kt * 32);
  }
  float bh[6];
  #pragma unroll
  for (int i = 0; i < 6; ++i)
    bh[i] = bhh[(i >> 1) * HQ + jbase + (i & 1) * 16 + l15];

  // xw staging: 1536 16B-chunks/step; wave w issues 3 calls of 64 chunks.
  // slot s -> (ch = s>>4, m = (s&15) ^ (ch&15))
  const u16* gsrc[3];
  int ldsoff[3];
  #pragma unroll
  for (int k = 0; k < 3; ++k) {
    int c0k = (w * 3 + k) * 64;
    int s = c0k + lane;
    int ch = s >> 4;
    int m = (s & 15) ^ (ch & 15);
    gsrc[k] = xw + (size_t)(b0 + m) * LQ * GQ + ch * 8;
    ldsoff[k] = c0k * 8;   // u16 units; +lane*16B by HW
  }
  // out readback: 1 chunk/thread (16 rows x 32 chunks)
  const int om = tid >> 5, oc = (tid & 31) * 8;

  // stage xw(0) into xwl[0]
  #pragma unroll
  for (int k = 0; k < 3; ++k) gl_lds16(gsrc[k], &xwl[0][ldsoff[k]]);

  __syncthreads();

  for (int t = 0; t < LQ; ++t) {
    const int rb = t & 1, wb = rb ^ 1;

    // async prefetch xw(t+1) -> xwl[wb]; drained by barrier at loop end
    const int tn = (t + 1 < LQ) ? t + 1 : t;
    #pragma unroll
    for (int k = 0; k < 3; ++k)
      gl_lds16(gsrc[k] + (size_t)tn * GQ, &xwl[wb][ldsoff[k]]);

    // A fragments from LDS h(t)
    short8 a[8];
    #pragma unroll
    for (int kt = 0; kt < 8; ++kt)
      a[kt] = ld8(&h_lds[rb][l15][kt * 32 + quad * 8]);

    // out(t-1) = h_lds[rb]: coalesced readback + nontemporal store
    if (t > 0) {
      short8 h0 = ld8(&h_lds[rb][om][oc]);
      st8nt(&out[((size_t)(b0 + om) * LQ + (t - 1)) * HQ + oc], h0);
    }

    // 2 j-slices; 3 gate accs live at a time; B from LDS cache where present
    #pragma unroll
    for (int jt = 0; jt < 2; ++jt) {
      f32x4 accr = {bh[jt], bh[jt], bh[jt], bh[jt]};
      f32x4 accz = {bh[2 + jt], bh[2 + jt], bh[2 + jt], bh[2 + jt]};
      f32x4 accn = {bh[4 + jt], bh[4 + jt], bh[4 + jt], bh[4 + jt]};
      const u16* bp0 = whh + (size_t)(jbase + jt * 16 + l15) * HQ + quad * 8;
      const u16* bp1 = bp0 + (size_t)HQ * HQ;
      const u16* bp2 = bp1 + (size_t)HQ * HQ;
      #pragma unroll
      for (int kt = 0; kt < 8; ++kt) {
        short8 br, bz, bn;
        if (kt < 2) {
          br = ld8(&wc[w][(0 * 2 + jt) * 2 + kt][lane * 8]);
          bz = ld8(&wc[w][(1 * 2 + jt) * 2 + kt][lane * 8]);
          bn = (jt == 0) ? ld8(&wc[w][(2 * 2 + jt) * 2 + kt][lane * 8])
                         : ld8(bp2 + kt * 32);
        } else {
          br = ld8(bp0 + kt * 32);
          bz = ld8(bp1 + kt * 32);
          bn = ld8(bp2 + kt * 32);
        }
        accr = mfma16(a[kt], br, accr);
        accz = mfma16(a[kt], bz, accz);
        accn = mfma16(a[kt], bn, accn);
      }
      const int j = jbase + jt * 16 + l15;
      #pragma unroll
      for (int reg = 0; reg < 4; ++reg) {
        const int m = quad * 4 + reg;
        const float xr = bfb2f(xwl[rb][xwl_idx(j, m)]);
        const float xz = bfb2f(xwl[rb][xwl_idx(HQ + j, m)]);
        const float xn = bfb2f(xwl[rb][xwl_idx(2 * HQ + j, m)]);
        const float hold = bfb2f(h_lds[rb][m][j]);
        const float rg = sigmf(accr[reg] + xr);
        const float zg = sigmf(accz[reg] + xz);
        const float ng = tanh_fast(fmaf(rg, accn[reg], xn));
        const float hn = fmaf(zg, hold - ng, ng);
        h_lds[wb][m][j] = f2bfb(hn);
      }
    }
    __syncthreads();
  }

  // final out(99): h(100) lives in h_lds[LQ & 1] == h_lds[0]
  {
    short8 h0 = ld8(&h_lds[0][om][oc]);
    st8nt(&out[((size_t)(b0 + om) * LQ + (LQ - 1)) * HQ + oc], h0);
  }
}

// ------- fused attention: q/e dots + softmax + windowed context ------------
__global__ __launch_bounds__(256) void attn_fused_kernel(
    const u16* __restrict__ out1, const u16* __restrict__ out2,
    const float* __restrict__ attn_w,
    u16* __restrict__ c1, u16* __restrict__ c2) {
  const int b = blockIdx.x;
  const int br = blockIdx.y;
  const u16* out = br ? out2 : out1;
  u16* cb = br ? c2 : c1;
  const int tid = threadIdx.x;
  const int w = tid >> 6, lane = tid & 63;

  __shared__ u16 ol[LQ][HPAD];
  __shared__ float qv[LQ], ev[LQ];

  for (int idx = tid; idx < LQ * 32; idx += 256) {
    int row = idx >> 5, c8 = (idx & 31) * 8;
    *(short8*)&ol[row][c8] = ld8(&out[((size_t)b * LQ + row) * HQ + c8]);
  }
  __syncthreads();

  float aq[4], ae[4];
  #pragma unroll
  for (int jj = 0; jj < 4; ++jj) {
    aq[jj] = attn_w[lane + 64 * jj];
    ae[jj] = attn_w[HQ + lane + 64 * jj];
  }
  for (int l = w; l < LQ; l += 4) {
    float sq = 0.f, se = 0.f;
    #pragma unroll
    for (int jj = 0; jj < 4; ++jj) {
      float v = bfb2f(ol[l][lane + 64 * jj]);
      sq = fmaf(v, aq[jj], sq);
      se = fmaf(v, ae[jj], se);
    }
    #pragma unroll
    for (int o = 32; o > 0; o >>= 1) { sq += __shfl_down(sq, o); se += __shfl_down(se, o); }
    if (lane == 0) { qv[l] = sq; ev[l] = se; }
  }
  __syncthreads();

  for (int m = 0; m < MQ; ++m) {
    const float qq = qv[m + WINQ];
    float s[WINQ];
    float mx = -1e30f;
    #pragma unroll
    for (int k = 0; k < WINQ; ++k) { s[k] = qq + ev[m + k]; mx = fmaxf(mx, s[k]); }
    float sum = 0.f;
    #pragma unroll
    for (int k = 0; k < WINQ; ++k) { s[k] = __expf(s[k] - mx); sum += s[k]; }
    const float inv = rcpf(sum);
    float accv = 0.f;
    #pragma unroll
    for (int k = 0; k < WINQ; ++k)
      accv = fmaf(s[k], bfb2f(ol[m + k][tid]), accv);
    cb[((size_t)b * MQ + m) * HQ + tid] = f2bfb(accv * inv);
  }
}

// ---------------- fused FC via MFMA: [c | out] @ fcW^T + fcb ---------------
__global__ __launch_bounds__(256) void fc_mfma_kernel(
    const u16* __restrict__ c1, const u16* __restrict__ c2,
    const u16* __restrict__ o1, const u16* __restrict__ o2,
    const u16* __restrict__ fcw, const float* __restrict__ fcb,
    u16* __restrict__ f1, u16* __restrict__ f2) {
  const int br = blockIdx.y;
  const u16* cb = br ? c2 : c1;
  const u16* ob = br ? o2 : o1;
  u16* fo = br ? f2 : f1;
  const int i0 = blockIdx.x * 64;
  const int tid = threadIdx.x;
  const int w = tid >> 6, lane = tid & 63, l15 = lane & 15, quad = lane >> 4;

  __shared__ u16 a_lds[64][520];
  for (int g = tid; g < 64 * 64; g += 256) {        // 16B groups, K=512
    int rr = g >> 6, c8 = (g & 63) * 8;
    int gi = i0 + rr;
    int bb = gi / MQ, mm = gi - bb * MQ;
    const u16* src = (c8 < HQ) ? &cb[(size_t)gi * HQ + c8]
                               : &ob[((size_t)bb * LQ + mm + WINQ) * HQ + (c8 - HQ)];
    *(short8*)&a_lds[rr][c8] = ld8(src);
  }
  __syncthreads();

  for (int nt = 0; nt < 4; ++nt) {
    const int n0 = w * 64 + nt * 16;
    const u16* bp = fcw + (size_t)(n0 + l15) * 512 + quad * 8;
    short8 b[16];
    #pragma unroll
    for (int kt = 0; kt < 16; ++kt) b[kt] = ld8(bp + kt * 32);
    const float bias = fcb[n0 + l15];
    #pragma unroll
    for (int mt = 0; mt < 4; ++mt) {
      f32x4 acc = {bias, bias, bias, bias};
      #pragma unroll
      for (int kt = 0; kt < 16; ++kt) {
        short8 a = ld8(&a_lds[mt * 16 + l15][kt * 32 + quad * 8]);
        acc = mfma16(a, b[kt], acc);
      }
      #pragma unroll
      for (int reg = 0; reg < 4; ++reg)
        fo[(size_t)(i0 + mt * 16 + quad * 4 + reg) * HQ + n0 + l15] = f2bfb(acc[reg]);
    }
  }
}

// ---------------- final head -----------------------------------------------
__global__ __launch_bounds__(256) void final_kernel(
    const bf16* __restrict__ out1,
    const bf16* __restrict__ f1, const bf16* __restrict__ f2,
    const float* __restrict__ outW, const float* __restrict__ outb,
    float* __restrict__ dout) {
  const int wid = blockIdx.x * 4 + (threadIdx.x >> 6);
  const int lane = threadIdx.x & 63;
  const int b = wid / LQ, l = wid - b * LQ;
  const bf16* s1 = (l < WINQ) ? (out1 + ((size_t)b * LQ + l) * HQ)
                              : (f1 + ((size_t)b * MQ + (l - WINQ)) * HQ);
  int l2 = l + 10;  // D = 10
  if (l2 > LQ - 1) l2 = LQ - 1;
  const bf16* s2 = f2 + ((size_t)b * MQ + (l2 - WINQ)) * HQ;
  float s = 0.0f;
  #pragma unroll
  for (int jj = 0; jj < 4; ++jj) {
    int h = lane + jj * 64;
    s = fmaf(bf2f(s1[h]), outW[h], s);
    s = fmaf(bf2f(s2[h]), outW[HQ + h], s);
  }
  #pragma unroll
  for (int o = 32; o > 0; o >>= 1) s += __shfl_down(s, o);
  if (lane == 0) dout[wid] = sigmf(s + outb[0]);
}

extern "C" void kernel_launch(void* const* d_in, const int* in_sizes, int n_in,
                              void* d_out, int out_size, void* d_ws, size_t ws_size,
                              hipStream_t stream) {
  const float* x       = (const float*)d_in[0];
  const float* r1_Wih0 = (const float*)d_in[1];
  const float* r1_Whh0 = (const float*)d_in[2];
  const float* r1_bih0 = (const float*)d_in[3];
  const float* r1_bhh0 = (const float*)d_in[4];
  const float* r1_Wih1 = (const float*)d_in[5];
  const float* r1_Whh1 = (const float*)d_in[6];
  const float* r1_bih1 = (const float*)d_in[7];
  const float* r1_bhh1 = (const float*)d_in[8];
  const float* r2_Wih0 = (const float*)d_in[9];
  const float* r2_Whh0 = (const float*)d_in[10];
  const float* r2_bih0 = (const float*)d_in[11];
  const float* r2_bhh0 = (const float*)d_in[12];
  const float* r2_Wih1 = (const float*)d_in[13];
  const float* r2_Whh1 = (const float*)d_in[14];
  const float* r2_bih1 = (const float*)d_in[15];
  const float* r2_bhh1 = (const float*)d_in[16];
  const float* attn_w  = (const float*)d_in[17];
  const float* fc_W    = (const float*)d_in[18];
  const float* fc_b    = (const float*)d_in[19];
  const float* out_W   = (const float*)d_in[20];
  const float* out_b   = (const float*)d_in[21];

  char* p = (char*)d_ws;
  auto carve = [&](size_t bytes) {
    char* r = p;
    p += ((bytes + 255) / 256) * 256;
    return r;
  };
  const size_t WSZ = (size_t)GQ * HQ;            // 196608 (Whh/Wih1)
  const size_t XWR = (size_t)BQ * LQ * GQ;       // 39,321,600 per receiver
  const size_t SEQ = (size_t)BQ * LQ * HQ;       // 13,107,200
  const size_t FSEQ = (size_t)BQ * MQ * HQ;      // 12,451,840

  u16* whh0A = (u16*)carve(WSZ * 2);
  u16* whh0B = (u16*)carve(WSZ * 2);
  u16* whh1A = (u16*)carve(WSZ * 2);
  u16* whh1B = (u16*)carve(WSZ * 2);
  u16* wih1A = (u16*)carve(WSZ * 2);
  u16* wih1B = (u16*)carve(WSZ * 2);
  u16* fcwbf = (u16*)carve((size_t)HQ * 512 * 2);
  u16* xwbuf = (u16*)carve(XWR * 2 * 2);         // both receivers; reused L0 then L1
  u16* obuf  = (u16*)carve(SEQ * 2 * 2);         // L0 out; later overwritten by L1 out

  u16* xwA = xwbuf;
  u16* xwB = xwbuf + XWR;
  u16* oA  = obuf;
  u16* oB  = obuf + SEQ;
  // c/f alias the xw region (dead after layer-1 scan)
  u16* c1 = xwbuf;
  u16* c2 = c1 + FSEQ;
  u16* f1 = c2 + FSEQ;
  u16* f2 = f1 + FSEQ;

  // all weight conversions, one launch
  cvt7_kernel<<<dim3((WSZ / 4 + 255) / 256, 7), 256, 0, stream>>>(
      r1_Whh0, r2_Whh0, r1_Whh1, r2_Whh1, r1_Wih1, r2_Wih1, fc_W,
      whh0A, whh0B, whh1A, whh1B, wih1A, wih1B, fcwbf);

  // layer 0
  xw0_kernel<<<dim3(BQ * LQ / 16, 2), 256, 0, stream>>>(
      x, r1_Wih0, r1_bih0, r2_Wih0, r2_bih0, xwbuf);
  scan_mfma_kernel<<<dim3(BQ / 16, 2), 512, 0, stream>>>(
      xwA, xwB, whh0A, whh0B, r1_bhh0, r2_bhh0, oA, oB);
  // layer 1
  xw1_gemm_kernel<<<dim3(BQ * LQ / 64, 2), 256, 0, stream>>>(
      oA, oB, wih1A, wih1B, r1_bih1, r2_bih1, xwbuf);
  scan_mfma_kernel<<<dim3(BQ / 16, 2), 512, 0, stream>>>(
      xwA, xwB, whh1A, whh1B, r1_bhh1, r2_bhh1, oA, oB);

  // branch
  attn_fused_kernel<<<dim3(BQ, 2), 256, 0, stream>>>(oA, oB, attn_w, c1, c2);
  fc_mfma_kernel<<<dim3((BQ * MQ) / 64, 2), 256, 0, stream>>>(c1, c2, oA, oB, fcwbf, fc_b, f1, f2);
  final_kernel<<<(BQ * LQ) / 4, 256, 0, stream>>>(
      (const bf16*)oA, (const bf16*)f1, (const bf16*)f2, out_W, out_b, (float*)d_out);
}